// Round 17
// baseline (195.993 us; speedup 1.0000x reference)
//
#include <hip/hip_runtime.h>
#include <hip/hip_fp16.h>

typedef _Float16 f16x8 __attribute__((ext_vector_type(8)));
typedef float f32x16 __attribute__((ext_vector_type(16)));

// LeNet C3 connection table: input channel ii feeds CONN[ii][j] with weight[j][ii].
__device__ constexpr int CONN[6][10] = {
    {0, 4, 5, 6, 9, 10, 11, 12, 14, 15},
    {0, 1, 5, 6, 7, 10, 11, 12, 13, 15},
    {0, 1, 2, 6, 7, 8, 11, 13, 14, 15},
    {1, 2, 3, 6, 7, 8, 9, 12, 14, 15},
    {2, 3, 4, 7, 8, 9, 10, 12, 13, 15},
    {3, 4, 5, 8, 9, 10, 11, 13, 14, 15}};

__device__ constexpr int CNT[16] = {3,3,3,3,3,3,4,4,4,4,4,4,4,4,4,6};

__device__ __forceinline__ f16x8 u4_to_h8(uint4 u) { f16x8 r; __builtin_memcpy(&r, &u, 16); return r; }

#define PITCH_DW 128            // pow2 pitch, no halo (wrap feeds only zero-weight/masked slots)
#define PLANE_DW 2048           // 16 rows x 128
#define PANEL_DW 12288          // panel starts here (6*2048); 3840 dw panel
#define LDS_DW   16128          // 64512 B total -> 2 blocks/CU

// Block: 256x x 12y tile, 4 waves, TWO resident 32-x strips per wave
// (full output page per phase -> clean write stream, R16-verified).
// L/H strip MFMA chains INTERLEAVED: two concurrent 15-chains per phase.
// Weight panel built in-LDS (no serial prep dispatch).
__global__ __launch_bounds__(256, 2) void c3_mfma(
    const float* __restrict__ x, const float* __restrict__ w,
    const float* __restrict__ bias, float* __restrict__ out)
{
    __shared__ unsigned s_lds[LDS_DW];
    unsigned short* s_panel = reinterpret_cast<unsigned short*>(s_lds + PANEL_DW);

    const int tid = threadIdx.x;
    // 1344 blocks = 64 n x 21 y-tiles; bijective XCD chunking (1344 = 8*168).
    const int id = (blockIdx.x & 7) * 168 + (blockIdx.x >> 3);
    const int by = id % 21;
    const int n  = id / 21;
    const int Y0 = by * 12;                 // rows Y0..Y0+15 staged; Y0 max 240 -> no guards
    const float* xin = x + (size_t)n * 6 * 65536;

    // ---- build weight A-panel in LDS (mfma_f32_32x32x16_f16, M=32, 15 MFMAs):
    // slice = ms + 15*kb; ii = slice/5; r = slice%5;
    // panel[(ms*64+lane)*8+j] = (ch<16 && j<5) ? w_full[ch][ii][r][j] : 0
    for (int t = tid; t < 7680; t += 256) {
        int j = t & 7, lane = (t >> 3) & 63, ms = t >> 9;
        int ch = lane & 31, kb = lane >> 5;
        int slice = ms + 15 * kb;
        int ii = slice / 5, r = slice % 5;
        float val = 0.f;
        if (ch < 16 && j < 5)
            for (int jj = 0; jj < 10; ++jj)
                if (CONN[ii][jj] == ch) val = w[jj * 150 + ii * 25 + r * 5 + j];
        __half h = __float2half(val);
        unsigned short u; __builtin_memcpy(&u, &h, 2);
        s_panel[t] = u;
    }

    // ---- stage 6ch x 16row x 256col f32 -> fp16 (pow2 indices, no guards) ----
    #pragma unroll 4
    for (int it = 0; it < 24; ++it) {
        int i   = tid + it * 256;          // 0..6143
        int c4  = i & 63;
        int row = (i >> 6) & 15;
        int ch  = i >> 10;
        float4 v = *reinterpret_cast<const float4*>(
            xin + (size_t)ch * 65536 + (size_t)(Y0 + row) * 256 + c4 * 4);
        __half2 lo = __floats2half2_rn(v.x, v.y);
        __half2 hi = __floats2half2_rn(v.z, v.w);
        uint2 u; __builtin_memcpy(&u.x, &lo, 4); __builtin_memcpy(&u.y, &hi, 4);
        *reinterpret_cast<uint2*>(&s_lds[ch * PLANE_DW + row * PITCH_DW + c4 * 2]) = u;
    }
    __syncthreads();

    const int lane = tid & 63;
    const int wv   = tid >> 6;
    const int nn   = lane & 31;    // B-col = x; C-col = x
    const int kb   = lane >> 5;    // plane-half selector; C rows += 4*kb

    // ---- weight A-frags from LDS panel ----
    f16x8 W[15];
    {
        const uint4* p4 = reinterpret_cast<const uint4*>(s_panel);
        #pragma unroll
        for (int ms = 0; ms < 15; ++ms) W[ms] = u4_to_h8(p4[ms * 64 + lane]);
    }

    // ---- C init: regs 0..7 = bias for ch=(reg&3)+8*(reg>>2)+4*kb; 8..15 = 0 ----
    f32x16 cinit;
    #pragma unroll
    for (int reg = 0; reg < 8; ++reg) {
        int ch = (reg & 3) + 8 * (reg >> 2) + 4 * kb;
        cinit[reg] = bias[ch] * (float)CNT[ch];
    }
    #pragma unroll
    for (int reg = 8; reg < 16; ++reg) cinit[reg] = 0.f;

    const int gxL = 32 * wv + nn;              // < 128, always valid
    const int gxH = 128 + gxL;                 // may exceed 251
    const bool okH = gxH < 252;
    const int pbL = 3 * kb * PLANE_DW + (gxL >> 1);
    const int pbH = 3 * kb * PLANE_DW + (gxH >> 1);
    const bool oddL = (gxL >> 1) & 1;
    const bool oddH = (gxH >> 1) & 1;
    const unsigned shb = (unsigned)((nn & 1) * 16);

    auto loadf = [&](int dw, bool odd) -> f16x8 {
        int d0 = dw & ~1;
        uint2 r0 = *reinterpret_cast<const uint2*>(&s_lds[d0]);
        uint2 r1 = *reinterpret_cast<const uint2*>(&s_lds[d0 + 2]);
        uint2 r2 = *reinterpret_cast<const uint2*>(&s_lds[d0 + 4]);
        unsigned e0 = odd ? r0.y : r0.x;
        unsigned e1 = odd ? r1.x : r0.y;
        unsigned e2 = odd ? r1.y : r1.x;
        unsigned e3 = odd ? r2.x : r1.y;
        unsigned e4 = odd ? r2.y : r2.x;
        unsigned o0 = (unsigned)((((unsigned long long)e1 << 32) | e0) >> shb);
        unsigned o1 = (unsigned)((((unsigned long long)e2 << 32) | e1) >> shb);
        unsigned o2 = (unsigned)((((unsigned long long)e3 << 32) | e2) >> shb);
        unsigned o3 = (unsigned)((((unsigned long long)e4 << 32) | e3) >> shb);
        return u4_to_h8(make_uint4(o0, o1, o2, o3));
    };

    // prologue: rows 0..4 x 3 planes x 2 strips
    f16x8 L00 = loadf(pbL + 0*PITCH_DW, oddL), L01 = loadf(pbL + 1*PITCH_DW, oddL),
          L02 = loadf(pbL + 2*PITCH_DW, oddL), L03 = loadf(pbL + 3*PITCH_DW, oddL),
          L04 = loadf(pbL + 4*PITCH_DW, oddL);
    f16x8 L10 = loadf(pbL + PLANE_DW + 0*PITCH_DW, oddL), L11 = loadf(pbL + PLANE_DW + 1*PITCH_DW, oddL),
          L12 = loadf(pbL + PLANE_DW + 2*PITCH_DW, oddL), L13 = loadf(pbL + PLANE_DW + 3*PITCH_DW, oddL),
          L14 = loadf(pbL + PLANE_DW + 4*PITCH_DW, oddL);
    f16x8 L20 = loadf(pbL + 2*PLANE_DW + 0*PITCH_DW, oddL), L21 = loadf(pbL + 2*PLANE_DW + 1*PITCH_DW, oddL),
          L22 = loadf(pbL + 2*PLANE_DW + 2*PITCH_DW, oddL), L23 = loadf(pbL + 2*PLANE_DW + 3*PITCH_DW, oddL),
          L24 = loadf(pbL + 2*PLANE_DW + 4*PITCH_DW, oddL);
    f16x8 H00 = loadf(pbH + 0*PITCH_DW, oddH), H01 = loadf(pbH + 1*PITCH_DW, oddH),
          H02 = loadf(pbH + 2*PITCH_DW, oddH), H03 = loadf(pbH + 3*PITCH_DW, oddH),
          H04 = loadf(pbH + 4*PITCH_DW, oddH);
    f16x8 H10 = loadf(pbH + PLANE_DW + 0*PITCH_DW, oddH), H11 = loadf(pbH + PLANE_DW + 1*PITCH_DW, oddH),
          H12 = loadf(pbH + PLANE_DW + 2*PITCH_DW, oddH), H13 = loadf(pbH + PLANE_DW + 3*PITCH_DW, oddH),
          H14 = loadf(pbH + PLANE_DW + 4*PITCH_DW, oddH);
    f16x8 H20 = loadf(pbH + 2*PLANE_DW + 0*PITCH_DW, oddH), H21 = loadf(pbH + 2*PLANE_DW + 1*PITCH_DW, oddH),
          H22 = loadf(pbH + 2*PLANE_DW + 2*PITCH_DW, oddH), H23 = loadf(pbH + 2*PLANE_DW + 3*PITCH_DW, oddH),
          H24 = loadf(pbH + 2*PLANE_DW + 4*PITCH_DW, oddH);
    int rowOff = 5 * PITCH_DW;

    float* const opL = out + (size_t)n * 16 * 63504 + (size_t)(4 * kb) * 63504 + gxL;
    float* const opH = opL + 128;
    int yoff = Y0 * 252;

#define MFMA32(a, b, c) __builtin_amdgcn_mfma_f32_32x32x16_f16(a, b, c, 0, 0, 0)

// Interleaved dual 15-chains: accL and accH progress together (2x ILP).
#define PHASE(l00,l01,l02,l03,l04, l10,l11,l12,l13,l14, l20,l21,l22,l23,l24,   \
              h00,h01,h02,h03,h04, h10,h11,h12,h13,h14, h20,h21,h22,h23,h24)   \
    {                                                                          \
        f32x16 accL = cinit, accH = cinit;                                     \
        accL = MFMA32(W[0],  l00, accL);  accH = MFMA32(W[0],  h00, accH);     \
        accL = MFMA32(W[1],  l01, accL);  accH = MFMA32(W[1],  h01, accH);     \
        accL = MFMA32(W[2],  l02, accL);  accH = MFMA32(W[2],  h02, accH);     \
        accL = MFMA32(W[3],  l03, accL);  accH = MFMA32(W[3],  h03, accH);     \
        accL = MFMA32(W[4],  l04, accL);  accH = MFMA32(W[4],  h04, accH);     \
        accL = MFMA32(W[5],  l10, accL);  accH = MFMA32(W[5],  h10, accH);     \
        accL = MFMA32(W[6],  l11, accL);  accH = MFMA32(W[6],  h11, accH);     \
        accL = MFMA32(W[7],  l12, accL);  accH = MFMA32(W[7],  h12, accH);     \
        accL = MFMA32(W[8],  l13, accL);  accH = MFMA32(W[8],  h13, accH);     \
        accL = MFMA32(W[9],  l14, accL);  accH = MFMA32(W[9],  h14, accH);     \
        accL = MFMA32(W[10], l20, accL);  accH = MFMA32(W[10], h20, accH);     \
        accL = MFMA32(W[11], l21, accL);  accH = MFMA32(W[11], h21, accH);     \
        accL = MFMA32(W[12], l22, accL);  accH = MFMA32(W[12], h22, accH);     \
        accL = MFMA32(W[13], l23, accL);  accH = MFMA32(W[13], h23, accH);     \
        accL = MFMA32(W[14], l24, accL);  accH = MFMA32(W[14], h24, accH);     \
        opL[yoff +  0 * 63504] = accL[0];                                      \
        opL[yoff +  1 * 63504] = accL[1];                                      \
        opL[yoff +  2 * 63504] = accL[2];                                      \
        opL[yoff +  3 * 63504] = accL[3];                                      \
        opL[yoff +  8 * 63504] = accL[4];                                      \
        opL[yoff +  9 * 63504] = accL[5];                                      \
        opL[yoff + 10 * 63504] = accL[6];                                      \
        opL[yoff + 11 * 63504] = accL[7];                                      \
        if (okH) {                                                             \
            opH[yoff +  0 * 63504] = accH[0];                                  \
            opH[yoff +  1 * 63504] = accH[1];                                  \
            opH[yoff +  2 * 63504] = accH[2];                                  \
            opH[yoff +  3 * 63504] = accH[3];                                  \
            opH[yoff +  8 * 63504] = accH[4];                                  \
            opH[yoff +  9 * 63504] = accH[5];                                  \
            opH[yoff + 10 * 63504] = accH[6];                                  \
            opH[yoff + 11 * 63504] = accH[7];                                  \
        }                                                                      \
        l00 = loadf(pbL + rowOff, oddL);                                       \
        l10 = loadf(pbL + PLANE_DW + rowOff, oddL);                            \
        l20 = loadf(pbL + 2 * PLANE_DW + rowOff, oddL);                        \
        h00 = loadf(pbH + rowOff, oddH);                                       \
        h10 = loadf(pbH + PLANE_DW + rowOff, oddH);                            \
        h20 = loadf(pbH + 2 * PLANE_DW + rowOff, oddH);                        \
        rowOff += PITCH_DW; yoff += 252;                                       \
    }
    // last phase's reload reads into panel/adjacent-plane region: in-bounds, unused

#define P(r0,r1,r2,r3,r4)                                                              \
    PHASE(L0##r0,L0##r1,L0##r2,L0##r3,L0##r4, L1##r0,L1##r1,L1##r2,L1##r3,L1##r4,      \
          L2##r0,L2##r1,L2##r2,L2##r3,L2##r4,                                          \
          H0##r0,H0##r1,H0##r2,H0##r3,H0##r4, H1##r0,H1##r1,H1##r2,H1##r3,H1##r4,      \
          H2##r0,H2##r1,H2##r2,H2##r3,H2##r4)

    P(0,1,2,3,4)
    P(1,2,3,4,0)
    P(2,3,4,0,1)
    P(3,4,0,1,2)
    P(4,0,1,2,3)
    P(0,1,2,3,4)
    P(1,2,3,4,0)
    P(2,3,4,0,1)
    P(3,4,0,1,2)
    P(4,0,1,2,3)
    P(0,1,2,3,4)
    P(1,2,3,4,0)
#undef P
#undef PHASE
#undef MFMA32
}

extern "C" void kernel_launch(void* const* d_in, const int* in_sizes, int n_in,
                              void* d_out, int out_size, void* d_ws, size_t ws_size,
                              hipStream_t stream) {
    const float* x    = (const float*)d_in[0];  // (64,6,256,256)
    const float* w    = (const float*)d_in[1];  // (10,6,5,5)
    const float* bias = (const float*)d_in[2];  // (1,16,1,1)
    float* out = (float*)d_out;                 // (64,16,252,252)

    hipLaunchKernelGGL(c3_mfma, dim3(1344), dim3(256), 0, stream, x, w, bias, out);
}